// Round 1
// baseline (33034.158 us; speedup 1.0000x reference)
//
#include <hip/hip_runtime.h>
#include <hip/hip_bf16.h>

#define T_SEQ 2048
#define HID 128
#define G4 512           // 4*HID gates
#define N_NODES 50000
#define N_EDGES 800000

__device__ __forceinline__ float sigmoidf_(float x) {
    return 1.0f / (1.0f + __expf(-x));
}

// ---------------- xg precompute, layer 0 (Din=17) ----------------
// grid: 2*T_SEQ*G4/256 blocks of 256. layout gid = ((dir*2048)+t)*512 + j
__global__ void xg0_kernel(const float* __restrict__ g_mol,
                           const float* __restrict__ wf, const float* __restrict__ bfi, const float* __restrict__ bfh,
                           const float* __restrict__ wr, const float* __restrict__ bri, const float* __restrict__ brh,
                           float* __restrict__ xg_f, float* __restrict__ xg_r)
{
    int gid = blockIdx.x * blockDim.x + threadIdx.x;
    int j = gid & (G4 - 1);
    int rest = gid >> 9;
    int t = rest & (T_SEQ - 1);
    int dir = rest >> 11;
    const float* w  = dir ? wr  : wf;
    const float* bi = dir ? bri : bfi;
    const float* bh = dir ? brh : bfh;
    float* xg = dir ? xg_r : xg_f;
    const float* x  = g_mol + t * 17;
    const float* wj = w + j * 17;
    float acc = bi[j] + bh[j];
    #pragma unroll
    for (int k = 0; k < 17; ++k) acc += x[k] * wj[k];
    xg[t * G4 + j] = acc;
}

// ---------------- xg precompute, layer 1 (Din=256 = concat[hf0,hr0]) ----------------
// layout gid = ((dir*512 + tb)*512 + j), each thread does 4 consecutive t for w-row reuse
__global__ void xg1_kernel(const float* __restrict__ hf0, const float* __restrict__ hr0,
                           const float* __restrict__ wf, const float* __restrict__ bfi, const float* __restrict__ bfh,
                           const float* __restrict__ wr, const float* __restrict__ bri, const float* __restrict__ brh,
                           float* __restrict__ xg_f, float* __restrict__ xg_r)
{
    int gid = blockIdx.x * blockDim.x + threadIdx.x;
    int j = gid & (G4 - 1);
    int rest = gid >> 9;
    int tb = rest & 511;
    int dir = rest >> 9;
    const float* w  = dir ? wr  : wf;
    const float* bi = dir ? bri : bfi;
    const float* bh = dir ? brh : bfh;
    float* xg = dir ? xg_r : xg_f;
    int t0 = tb * 4;

    float b = bi[j] + bh[j];
    float a0 = b, a1 = b, a2 = b, a3 = b;
    const float4* wrow = reinterpret_cast<const float4*>(w + j * 256);
    const float4* hf = reinterpret_cast<const float4*>(hf0 + t0 * HID);
    const float4* hr = reinterpret_cast<const float4*>(hr0 + t0 * HID);
    #pragma unroll 8
    for (int k = 0; k < 32; ++k) {
        float4 wv = wrow[k];
        float4 v0 = hf[k], v1 = hf[32 + k], v2 = hf[64 + k], v3 = hf[96 + k];
        a0 += wv.x*v0.x + wv.y*v0.y + wv.z*v0.z + wv.w*v0.w;
        a1 += wv.x*v1.x + wv.y*v1.y + wv.z*v1.z + wv.w*v1.w;
        a2 += wv.x*v2.x + wv.y*v2.y + wv.z*v2.z + wv.w*v2.w;
        a3 += wv.x*v3.x + wv.y*v3.y + wv.z*v3.z + wv.w*v3.w;
    }
    #pragma unroll 8
    for (int k = 0; k < 32; ++k) {
        float4 wv = wrow[32 + k];
        float4 v0 = hr[k], v1 = hr[32 + k], v2 = hr[64 + k], v3 = hr[96 + k];
        a0 += wv.x*v0.x + wv.y*v0.y + wv.z*v0.z + wv.w*v0.w;
        a1 += wv.x*v1.x + wv.y*v1.y + wv.z*v1.z + wv.w*v1.w;
        a2 += wv.x*v2.x + wv.y*v2.y + wv.z*v2.z + wv.w*v2.w;
        a3 += wv.x*v3.x + wv.y*v3.y + wv.z*v3.z + wv.w*v3.w;
    }
    xg[(t0 + 0) * G4 + j] = a0;
    xg[(t0 + 1) * G4 + j] = a1;
    xg[(t0 + 2) * G4 + j] = a2;
    xg[(t0 + 3) * G4 + j] = a3;
}

// ---------------- the sequential LSTM scan: one block per direction ----------------
// 512 threads; thread j owns gate row j (w_hh[j,:] in 128 VGPRs). h broadcast via LDS.
__global__ __launch_bounds__(512, 2)
void lstm_scan(const float* __restrict__ xg_f, const float* __restrict__ xg_r,
               const float* __restrict__ whh_f, const float* __restrict__ whh_r,
               float* __restrict__ out_f, float* __restrict__ out_r,
               float* __restrict__ gvec, int write_out)
{
    const int dir = blockIdx.x;            // 0 fwd, 1 rev
    const int j = threadIdx.x;             // 0..511
    const float* xg  = dir ? xg_r  : xg_f;
    const float* whh = dir ? whh_r : whh_f;
    float* out = dir ? out_r : out_f;

    __shared__ float h_s[HID];
    __shared__ float g_s[G4];

    float4 w[32];
    const float4* wrow = reinterpret_cast<const float4*>(whh + j * HID);
    #pragma unroll
    for (int k = 0; k < 32; ++k) w[k] = wrow[k];

    if (j < HID) h_s[j] = 0.0f;
    float c = 0.0f;
    float msum = 0.0f;
    __syncthreads();

    int t0 = dir ? (T_SEQ - 1) : 0;
    float xv = xg[t0 * G4 + j];            // prefetched current-step input gate

    for (int s = 0; s < T_SEQ; ++s) {
        int s2 = (s + 1 < T_SEQ) ? (s + 1) : s;
        int t      = dir ? (T_SEQ - 1 - s)  : s;
        int t_next = dir ? (T_SEQ - 1 - s2) : s2;
        float xv_n = xg[t_next * G4 + j];  // prefetch next step (hidden under the dot)

        float acc = 0.0f;
        const float4* h4 = reinterpret_cast<const float4*>(h_s);
        #pragma unroll 8
        for (int k = 0; k < 32; ++k) {
            float4 hv = h4[k];
            acc += w[k].x * hv.x + w[k].y * hv.y + w[k].z * hv.z + w[k].w * hv.w;
        }
        g_s[j] = acc + xv;
        __syncthreads();
        if (j < HID) {
            float ig = sigmoidf_(g_s[j]);
            float fg = sigmoidf_(g_s[HID + j]);
            float gg = tanhf(g_s[2 * HID + j]);
            float og = sigmoidf_(g_s[3 * HID + j]);
            c = fg * c + ig * gg;
            float hh = og * tanhf(c);
            h_s[j] = hh;
            if (write_out) out[t * HID + j] = hh;
            msum += hh;
        }
        __syncthreads();
        xv = xv_n;
    }
    if (gvec != nullptr && j < HID) gvec[dir * HID + j] = msum * (1.0f / (float)T_SEQ);
}

// ---------------- GraphConv hop 1: weighted scatter-add ----------------
// thread = (edge, 4-feature chunk); grid = N_EDGES*32/256
__global__ void scatter_kernel(const int* __restrict__ esrc, const int* __restrict__ edst,
                               const float* __restrict__ ew, const float* __restrict__ feat,
                               float* __restrict__ agg)
{
    int gid = blockIdx.x * blockDim.x + threadIdx.x;
    int e = gid >> 5;
    int c = gid & 31;
    int s = esrc[e], d = edst[e];
    float w = ew[e];
    float4 v = reinterpret_cast<const float4*>(feat)[(long)s * 32 + c];
    float* ap = agg + (long)d * HID + (c << 2);
    atomicAdd(ap + 0, w * v.x);
    atomicAdd(ap + 1, w * v.y);
    atomicAdd(ap + 2, w * v.z);
    atomicAdd(ap + 3, w * v.w);
}

// ---------------- hop 1 linear + relu, in-place on agg, W1 staged in LDS ----------------
#define NPB 50
__global__ __launch_bounds__(128)
void gconv1_kernel(const float* __restrict__ W1, const float* __restrict__ b1,
                   float* __restrict__ agg)
{
    __shared__ float w_s[128 * 128];   // 64 KB
    __shared__ float row_s[2][HID];
    int j = threadIdx.x;
    for (int i = j; i < 128 * 128; i += 128) w_s[i] = W1[i];
    float bj = b1[j];
    __syncthreads();
    int base = blockIdx.x * NPB;
    for (int n = base; n < base + NPB; n += 2) {
        row_s[0][j] = agg[(long)n * HID + j];
        row_s[1][j] = agg[(long)(n + 1) * HID + j];
        __syncthreads();
        float a0 = bj, a1 = bj;
        #pragma unroll 8
        for (int k = 0; k < 128; ++k) {
            float w = w_s[k * 128 + j];
            a0 += row_s[0][k] * w;
            a1 += row_s[1][k] * w;
        }
        __syncthreads();   // everyone done reading row_s before next overwrite
        agg[(long)n * HID + j]       = fmaxf(a0, 0.0f);
        agg[(long)(n + 1) * HID + j] = fmaxf(a1, 0.0f);
    }
}

// ---------------- hop 2 collapsed: s[k] = sum_e w_e * h[src_e][k] ----------------
__global__ void hop2_reduce(const int* __restrict__ esrc, const float* __restrict__ ew,
                            const float* __restrict__ h, float* __restrict__ s_out)
{
    int tid = threadIdx.x;        // 256 = 8 edge-lanes x 32 chunks
    int c = tid & 31;
    int g = tid >> 5;
    float ax = 0.f, ay = 0.f, az = 0.f, aw = 0.f;
    const float4* h4 = reinterpret_cast<const float4*>(h);
    for (long e = (long)blockIdx.x * 8 + g; e < N_EDGES; e += (long)gridDim.x * 8) {
        float wgt = ew[e];
        int sidx = esrc[e];
        float4 v = h4[(long)sidx * 32 + c];
        ax += wgt * v.x; ay += wgt * v.y; az += wgt * v.z; aw += wgt * v.w;
    }
    __shared__ float red[256 * 4];
    red[tid * 4 + 0] = ax; red[tid * 4 + 1] = ay;
    red[tid * 4 + 2] = az; red[tid * 4 + 3] = aw;
    __syncthreads();
    if (tid < 32) {
        float r0 = 0.f, r1 = 0.f, r2 = 0.f, r3 = 0.f;
        for (int gg = 0; gg < 8; ++gg) {
            int b = (gg * 32 + tid) * 4;
            r0 += red[b + 0]; r1 += red[b + 1]; r2 += red[b + 2]; r3 += red[b + 3];
        }
        atomicAdd(&s_out[tid * 4 + 0], r0);
        atomicAdd(&s_out[tid * 4 + 1], r1);
        atomicAdd(&s_out[tid * 4 + 2], r2);
        atomicAdd(&s_out[tid * 4 + 3], r3);
    }
}

// ---------------- head: hg = (s/N)@W2 + b2; concat; 4-layer MLP ----------------
__global__ __launch_bounds__(640)
void head_kernel(const float* __restrict__ s_in, const float* __restrict__ W2, const float* __restrict__ b2,
                 const float* __restrict__ gvec, const float* __restrict__ kmer,
                 const float* __restrict__ fc1w, const float* __restrict__ fc1b,
                 const float* __restrict__ fc2w, const float* __restrict__ fc2b,
                 const float* __restrict__ fc3w, const float* __restrict__ fc3b,
                 const float* __restrict__ fc4w, const float* __restrict__ fc4b,
                 float* __restrict__ out)
{
    __shared__ float feat[1152];
    __shared__ float a1[576];
    __shared__ float a2[256];
    __shared__ float a3[64];
    int tid = threadIdx.x;
    if (tid < 256) {
        float acc = b2[tid];
        const float inv_n = 1.0f / (float)N_NODES;
        for (int k = 0; k < HID; ++k)
            acc += (s_in[k] * inv_n) * W2[k * 256 + tid];
        feat[tid] = acc;
    } else if (tid < 512) {
        feat[tid] = gvec[tid - 256];
    }
    if (tid < 638) feat[512 + tid] = kmer[tid];
    __syncthreads();

    if (tid < 575) {
        const float2* wr = reinterpret_cast<const float2*>(fc1w + (long)tid * 1150);
        const float2* f2 = reinterpret_cast<const float2*>(feat);
        float acc = fc1b[tid];
        for (int k = 0; k < 575; ++k) {
            float2 wv = wr[k]; float2 fv = f2[k];
            acc += wv.x * fv.x + wv.y * fv.y;
        }
        a1[tid] = fmaxf(acc, 0.0f);
    }
    __syncthreads();
    if (tid < 256) {
        const float* wr = fc2w + (long)tid * 575;
        float acc = fc2b[tid];
        for (int k = 0; k < 575; ++k) acc += a1[k] * wr[k];
        a2[tid] = fmaxf(acc, 0.0f);
    }
    __syncthreads();
    if (tid < 64) {
        const float4* wr = reinterpret_cast<const float4*>(fc3w + (long)tid * 256);
        const float4* av4 = reinterpret_cast<const float4*>(a2);
        float acc = fc3b[tid];
        for (int k = 0; k < 64; ++k) {
            float4 wv = wr[k]; float4 av = av4[k];
            acc += wv.x*av.x + wv.y*av.y + wv.z*av.z + wv.w*av.w;
        }
        a3[tid] = fmaxf(acc, 0.0f);
    }
    __syncthreads();
    if (tid == 0) {
        float acc = fc4b[0];
        for (int k = 0; k < 64; ++k) acc += a3[k] * fc4w[k];
        out[0] = acc;
    }
}

extern "C" void kernel_launch(void* const* d_in, const int* in_sizes, int n_in,
                              void* d_out, int out_size, void* d_ws, size_t ws_size,
                              hipStream_t stream)
{
    const float* g_mol = (const float*)d_in[0];
    const float* feat  = (const float*)d_in[1];
    const int*   esrc  = (const int*)d_in[2];
    const int*   edst  = (const int*)d_in[3];
    const float* ew    = (const float*)d_in[4];
    const float* kmer  = (const float*)d_in[5];
    const float* w_ih_l0  = (const float*)d_in[6];
    const float* w_hh_l0  = (const float*)d_in[7];
    const float* b_ih_l0  = (const float*)d_in[8];
    const float* b_hh_l0  = (const float*)d_in[9];
    const float* w_ih_l0r = (const float*)d_in[10];
    const float* w_hh_l0r = (const float*)d_in[11];
    const float* b_ih_l0r = (const float*)d_in[12];
    const float* b_hh_l0r = (const float*)d_in[13];
    const float* w_ih_l1  = (const float*)d_in[14];
    const float* w_hh_l1  = (const float*)d_in[15];
    const float* b_ih_l1  = (const float*)d_in[16];
    const float* b_hh_l1  = (const float*)d_in[17];
    const float* w_ih_l1r = (const float*)d_in[18];
    const float* w_hh_l1r = (const float*)d_in[19];
    const float* b_ih_l1r = (const float*)d_in[20];
    const float* b_hh_l1r = (const float*)d_in[21];
    const float* W1 = (const float*)d_in[22];
    const float* b1 = (const float*)d_in[23];
    const float* W2 = (const float*)d_in[24];
    const float* b2 = (const float*)d_in[25];
    const float* fc1w = (const float*)d_in[26];
    const float* fc1b = (const float*)d_in[27];
    const float* fc2w = (const float*)d_in[28];
    const float* fc2b = (const float*)d_in[29];
    const float* fc3w = (const float*)d_in[30];
    const float* fc3b = (const float*)d_in[31];
    const float* fc4w = (const float*)d_in[32];
    const float* fc4b = (const float*)d_in[33];

    float* ws  = (float*)d_ws;
    float* XGF  = ws;                          // [2048*512]
    float* XGR  = XGF + T_SEQ * G4;            // [2048*512]
    float* HF0  = XGR + T_SEQ * G4;            // [2048*128]
    float* HR0  = HF0 + T_SEQ * HID;           // [2048*128]
    float* GVEC = HR0 + T_SEQ * HID;           // [256]
    float* SUM  = GVEC + 256;                  // [128]
    float* AGG  = SUM + 128;                   // [50000*128]

    hipMemsetAsync(AGG, 0, (size_t)N_NODES * HID * sizeof(float), stream);
    hipMemsetAsync(SUM, 0, 128 * sizeof(float), stream);

    // ---- graph branch ----
    scatter_kernel<<<(N_EDGES * 32) / 256, 256, 0, stream>>>(esrc, edst, ew, feat, AGG);
    gconv1_kernel<<<N_NODES / NPB, 128, 0, stream>>>(W1, b1, AGG);
    hop2_reduce<<<2048, 256, 0, stream>>>(esrc, ew, AGG, SUM);

    // ---- LSTM branch ----
    xg0_kernel<<<(2 * T_SEQ * G4) / 256, 256, 0, stream>>>(
        g_mol, w_ih_l0, b_ih_l0, b_hh_l0, w_ih_l0r, b_ih_l0r, b_hh_l0r, XGF, XGR);
    lstm_scan<<<2, 512, 0, stream>>>(XGF, XGR, w_hh_l0, w_hh_l0r, HF0, HR0, nullptr, 1);
    xg1_kernel<<<(2 * 512 * G4) / 256, 256, 0, stream>>>(
        HF0, HR0, w_ih_l1, b_ih_l1, b_hh_l1, w_ih_l1r, b_ih_l1r, b_hh_l1r, XGF, XGR);
    lstm_scan<<<2, 512, 0, stream>>>(XGF, XGR, w_hh_l1, w_hh_l1r, nullptr, nullptr, GVEC, 0);

    // ---- head ----
    head_kernel<<<1, 640, 0, stream>>>(SUM, W2, b2, GVEC, kmer,
                                       fc1w, fc1b, fc2w, fc2b, fc3w, fc3b, fc4w, fc4b,
                                       (float*)d_out);
}

// Round 3
// 7862.423 us; speedup vs baseline: 4.2015x; 4.2015x over previous
//
#include <hip/hip_runtime.h>
#include <hip/hip_bf16.h>

#define T_SEQ 2048
#define HID 128
#define G4 512           // 4*HID gates
#define N_NODES 50000
#define N_EDGES 800000

__device__ __forceinline__ float fast_sigmoid(float x) {
    return 1.0f / (1.0f + __expf(-x));
}
__device__ __forceinline__ float fast_tanh(float x) {
    // NaN-safe: x->+inf => 1-0, x->-inf => 1-2
    return 1.0f - 2.0f / (__expf(2.0f * x) + 1.0f);
}

// ---------------- xg precompute, layer 0 (Din=17) ----------------
__global__ void xg0_kernel(const float* __restrict__ g_mol,
                           const float* __restrict__ wf, const float* __restrict__ bfi, const float* __restrict__ bfh,
                           const float* __restrict__ wr, const float* __restrict__ bri, const float* __restrict__ brh,
                           float* __restrict__ xg_f, float* __restrict__ xg_r)
{
    int gid = blockIdx.x * blockDim.x + threadIdx.x;
    int j = gid & (G4 - 1);
    int rest = gid >> 9;
    int t = rest & (T_SEQ - 1);
    int dir = rest >> 11;
    const float* w  = dir ? wr  : wf;
    const float* bi = dir ? bri : bfi;
    const float* bh = dir ? brh : bfh;
    float* xg = dir ? xg_r : xg_f;
    const float* x  = g_mol + t * 17;
    const float* wj = w + j * 17;
    float acc = bi[j] + bh[j];
    #pragma unroll
    for (int k = 0; k < 17; ++k) acc += x[k] * wj[k];
    xg[t * G4 + j] = acc;
}

// ---------------- xg precompute, layer 1 (Din=256 = concat[hf0,hr0]) ----------------
__global__ void xg1_kernel(const float* __restrict__ hf0, const float* __restrict__ hr0,
                           const float* __restrict__ wf, const float* __restrict__ bfi, const float* __restrict__ bfh,
                           const float* __restrict__ wr, const float* __restrict__ bri, const float* __restrict__ brh,
                           float* __restrict__ xg_f, float* __restrict__ xg_r)
{
    int gid = blockIdx.x * blockDim.x + threadIdx.x;
    int j = gid & (G4 - 1);
    int rest = gid >> 9;
    int tb = rest & 511;
    int dir = rest >> 9;
    const float* w  = dir ? wr  : wf;
    const float* bi = dir ? bri : bfi;
    const float* bh = dir ? brh : bfh;
    float* xg = dir ? xg_r : xg_f;
    int t0 = tb * 4;

    float b = bi[j] + bh[j];
    float a0 = b, a1 = b, a2 = b, a3 = b;
    const float4* wrow = reinterpret_cast<const float4*>(w + j * 256);
    const float4* hf = reinterpret_cast<const float4*>(hf0 + t0 * HID);
    const float4* hr = reinterpret_cast<const float4*>(hr0 + t0 * HID);
    #pragma unroll 8
    for (int k = 0; k < 32; ++k) {
        float4 wv = wrow[k];
        float4 v0 = hf[k], v1 = hf[32 + k], v2 = hf[64 + k], v3 = hf[96 + k];
        a0 += wv.x*v0.x + wv.y*v0.y + wv.z*v0.z + wv.w*v0.w;
        a1 += wv.x*v1.x + wv.y*v1.y + wv.z*v1.z + wv.w*v1.w;
        a2 += wv.x*v2.x + wv.y*v2.y + wv.z*v2.z + wv.w*v2.w;
        a3 += wv.x*v3.x + wv.y*v3.y + wv.z*v3.z + wv.w*v3.w;
    }
    #pragma unroll 8
    for (int k = 0; k < 32; ++k) {
        float4 wv = wrow[32 + k];
        float4 v0 = hr[k], v1 = hr[32 + k], v2 = hr[64 + k], v3 = hr[96 + k];
        a0 += wv.x*v0.x + wv.y*v0.y + wv.z*v0.z + wv.w*v0.w;
        a1 += wv.x*v1.x + wv.y*v1.y + wv.z*v1.z + wv.w*v1.w;
        a2 += wv.x*v2.x + wv.y*v2.y + wv.z*v2.z + wv.w*v2.w;
        a3 += wv.x*v3.x + wv.y*v3.y + wv.z*v3.z + wv.w*v3.w;
    }
    xg[(t0 + 0) * G4 + j] = a0;
    xg[(t0 + 1) * G4 + j] = a1;
    xg[(t0 + 2) * G4 + j] = a2;
    xg[(t0 + 3) * G4 + j] = a3;
}

// ---------------- the sequential LSTM scan: one block per direction ----------------
// 512 threads; thread j owns gate row j. w_hh row fully unrolled into VGPRs
// (FULL unroll is mandatory: partial unroll -> runtime index -> scratch spill,
//  seen in R1 as VGPR_Count=32 + 5.3 GB FETCH_SIZE).
__global__ __launch_bounds__(512, 2)
void lstm_scan(const float* __restrict__ xg_f, const float* __restrict__ xg_r,
               const float* __restrict__ whh_f, const float* __restrict__ whh_r,
               float* __restrict__ out_f, float* __restrict__ out_r,
               float* __restrict__ gvec, int write_out)
{
    const int dir = blockIdx.x;            // 0 fwd, 1 rev
    const int j = threadIdx.x;             // 0..511
    const float* xg  = dir ? xg_r  : xg_f;
    const float* whh = dir ? whh_r : whh_f;
    float* out = dir ? out_r : out_f;

    __shared__ float h_s[HID];
    __shared__ float g_s[G4];

    float4 w4[32];
    const float4* wrow = reinterpret_cast<const float4*>(whh + j * HID);
    #pragma unroll
    for (int k = 0; k < 32; ++k) w4[k] = wrow[k];

    if (j < HID) h_s[j] = 0.0f;
    float c = 0.0f;
    float msum = 0.0f;
    __syncthreads();

    int t0 = dir ? (T_SEQ - 1) : 0;
    float xv = xg[t0 * G4 + j];            // prefetched current-step input gate

    for (int s = 0; s < T_SEQ; ++s) {
        int s2 = (s + 1 < T_SEQ) ? (s + 1) : s;
        int t      = dir ? (T_SEQ - 1 - s)  : s;
        int t_next = dir ? (T_SEQ - 1 - s2) : s2;
        float xv_n = xg[t_next * G4 + j];  // prefetch next step (hidden under the dot)

        const float4* h4 = reinterpret_cast<const float4*>(h_s);
        float a0 = 0.f, a1 = 0.f, a2 = 0.f, a3 = 0.f;
        #pragma unroll
        for (int k = 0; k < 32; ++k) {     // FULL unroll: static w4[k] indices
            float4 hv = h4[k];
            a0 += w4[k].x * hv.x;
            a1 += w4[k].y * hv.y;
            a2 += w4[k].z * hv.z;
            a3 += w4[k].w * hv.w;
        }
        g_s[j] = (a0 + a1) + (a2 + a3) + xv;
        __syncthreads();
        if (j < HID) {
            float ig = fast_sigmoid(g_s[j]);
            float fg = fast_sigmoid(g_s[HID + j]);
            float gg = fast_tanh(g_s[2 * HID + j]);
            float og = fast_sigmoid(g_s[3 * HID + j]);
            c = fg * c + ig * gg;
            float hh = og * fast_tanh(c);
            h_s[j] = hh;
            if (write_out) out[t * HID + j] = hh;
            msum += hh;
        }
        __syncthreads();
        xv = xv_n;
    }
    if (gvec != nullptr && j < HID) gvec[dir * HID + j] = msum * (1.0f / (float)T_SEQ);
}

// ---------------- GraphConv hop 1: weighted scatter-add ----------------
__global__ void scatter_kernel(const int* __restrict__ esrc, const int* __restrict__ edst,
                               const float* __restrict__ ew, const float* __restrict__ feat,
                               float* __restrict__ agg)
{
    int gid = blockIdx.x * blockDim.x + threadIdx.x;
    int e = gid >> 5;
    int c = gid & 31;
    int s = esrc[e], d = edst[e];
    float w = ew[e];
    float4 v = reinterpret_cast<const float4*>(feat)[(long)s * 32 + c];
    float* ap = agg + (long)d * HID + (c << 2);
    atomicAdd(ap + 0, w * v.x);
    atomicAdd(ap + 1, w * v.y);
    atomicAdd(ap + 2, w * v.z);
    atomicAdd(ap + 3, w * v.w);
}

// ---------------- hop 1 linear + relu, in-place on agg, W1 staged in LDS ----------------
#define NPB 50
__global__ __launch_bounds__(128)
void gconv1_kernel(const float* __restrict__ W1, const float* __restrict__ b1,
                   float* __restrict__ agg)
{
    __shared__ float w_s[128 * 128];   // 64 KB
    __shared__ float row_s[2][HID];
    int j = threadIdx.x;
    for (int i = j; i < 128 * 128; i += 128) w_s[i] = W1[i];
    float bj = b1[j];
    __syncthreads();
    int base = blockIdx.x * NPB;
    for (int n = base; n < base + NPB; n += 2) {
        row_s[0][j] = agg[(long)n * HID + j];
        row_s[1][j] = agg[(long)(n + 1) * HID + j];
        __syncthreads();
        float a0 = bj, a1 = bj;
        #pragma unroll 8
        for (int k = 0; k < 128; ++k) {
            float w = w_s[k * 128 + j];
            a0 += row_s[0][k] * w;
            a1 += row_s[1][k] * w;
        }
        __syncthreads();
        agg[(long)n * HID + j]       = fmaxf(a0, 0.0f);
        agg[(long)(n + 1) * HID + j] = fmaxf(a1, 0.0f);
    }
}

// ---------------- hop 2 collapsed: s[k] = sum_e w_e * h[src_e][k] ----------------
__global__ void hop2_reduce(const int* __restrict__ esrc, const float* __restrict__ ew,
                            const float* __restrict__ h, float* __restrict__ s_out)
{
    int tid = threadIdx.x;        // 256 = 8 edge-lanes x 32 chunks
    int c = tid & 31;
    int g = tid >> 5;
    float ax = 0.f, ay = 0.f, az = 0.f, aw = 0.f;
    const float4* h4 = reinterpret_cast<const float4*>(h);
    for (long e = (long)blockIdx.x * 8 + g; e < N_EDGES; e += (long)gridDim.x * 8) {
        float wgt = ew[e];
        int sidx = esrc[e];
        float4 v = h4[(long)sidx * 32 + c];
        ax += wgt * v.x; ay += wgt * v.y; az += wgt * v.z; aw += wgt * v.w;
    }
    __shared__ float red[256 * 4];
    red[tid * 4 + 0] = ax; red[tid * 4 + 1] = ay;
    red[tid * 4 + 2] = az; red[tid * 4 + 3] = aw;
    __syncthreads();
    if (tid < 32) {
        float r0 = 0.f, r1 = 0.f, r2 = 0.f, r3 = 0.f;
        for (int gg = 0; gg < 8; ++gg) {
            int b = (gg * 32 + tid) * 4;
            r0 += red[b + 0]; r1 += red[b + 1]; r2 += red[b + 2]; r3 += red[b + 3];
        }
        atomicAdd(&s_out[tid * 4 + 0], r0);
        atomicAdd(&s_out[tid * 4 + 1], r1);
        atomicAdd(&s_out[tid * 4 + 2], r2);
        atomicAdd(&s_out[tid * 4 + 3], r3);
    }
}

// ---------------- head: hg = (s/N)@W2 + b2; concat; 4-layer MLP ----------------
__global__ __launch_bounds__(640)
void head_kernel(const float* __restrict__ s_in, const float* __restrict__ W2, const float* __restrict__ b2,
                 const float* __restrict__ gvec, const float* __restrict__ kmer,
                 const float* __restrict__ fc1w, const float* __restrict__ fc1b,
                 const float* __restrict__ fc2w, const float* __restrict__ fc2b,
                 const float* __restrict__ fc3w, const float* __restrict__ fc3b,
                 const float* __restrict__ fc4w, const float* __restrict__ fc4b,
                 float* __restrict__ out)
{
    __shared__ float feat[1152];
    __shared__ float a1[576];
    __shared__ float a2[256];
    __shared__ float a3[64];
    int tid = threadIdx.x;
    if (tid < 256) {
        float acc = b2[tid];
        const float inv_n = 1.0f / (float)N_NODES;
        for (int k = 0; k < HID; ++k)
            acc += (s_in[k] * inv_n) * W2[k * 256 + tid];
        feat[tid] = acc;
    } else if (tid < 512) {
        feat[tid] = gvec[tid - 256];
    }
    if (tid < 638) feat[512 + tid] = kmer[tid];
    __syncthreads();

    if (tid < 575) {
        const float2* wr = reinterpret_cast<const float2*>(fc1w + (long)tid * 1150);
        const float2* f2 = reinterpret_cast<const float2*>(feat);
        float acc = fc1b[tid];
        for (int k = 0; k < 575; ++k) {
            float2 wv = wr[k]; float2 fv = f2[k];
            acc += wv.x * fv.x + wv.y * fv.y;
        }
        a1[tid] = fmaxf(acc, 0.0f);
    }
    __syncthreads();
    if (tid < 256) {
        const float* wr = fc2w + (long)tid * 575;
        float acc = fc2b[tid];
        for (int k = 0; k < 575; ++k) acc += a1[k] * wr[k];
        a2[tid] = fmaxf(acc, 0.0f);
    }
    __syncthreads();
    if (tid < 64) {
        const float4* wr = reinterpret_cast<const float4*>(fc3w + (long)tid * 256);
        const float4* av4 = reinterpret_cast<const float4*>(a2);
        float acc = fc3b[tid];
        for (int k = 0; k < 64; ++k) {
            float4 wv = wr[k]; float4 av = av4[k];
            acc += wv.x*av.x + wv.y*av.y + wv.z*av.z + wv.w*av.w;
        }
        a3[tid] = fmaxf(acc, 0.0f);
    }
    __syncthreads();
    if (tid == 0) {
        float acc = fc4b[0];
        for (int k = 0; k < 64; ++k) acc += a3[k] * fc4w[k];
        out[0] = acc;
    }
}

extern "C" void kernel_launch(void* const* d_in, const int* in_sizes, int n_in,
                              void* d_out, int out_size, void* d_ws, size_t ws_size,
                              hipStream_t stream)
{
    const float* g_mol = (const float*)d_in[0];
    const float* feat  = (const float*)d_in[1];
    const int*   esrc  = (const int*)d_in[2];
    const int*   edst  = (const int*)d_in[3];
    const float* ew    = (const float*)d_in[4];
    const float* kmer  = (const float*)d_in[5];
    const float* w_ih_l0  = (const float*)d_in[6];
    const float* w_hh_l0  = (const float*)d_in[7];
    const float* b_ih_l0  = (const float*)d_in[8];
    const float* b_hh_l0  = (const float*)d_in[9];
    const float* w_ih_l0r = (const float*)d_in[10];
    const float* w_hh_l0r = (const float*)d_in[11];
    const float* b_ih_l0r = (const float*)d_in[12];
    const float* b_hh_l0r = (const float*)d_in[13];
    const float* w_ih_l1  = (const float*)d_in[14];
    const float* w_hh_l1  = (const float*)d_in[15];
    const float* b_ih_l1  = (const float*)d_in[16];
    const float* b_hh_l1  = (const float*)d_in[17];
    const float* w_ih_l1r = (const float*)d_in[18];
    const float* w_hh_l1r = (const float*)d_in[19];
    const float* b_ih_l1r = (const float*)d_in[20];
    const float* b_hh_l1r = (const float*)d_in[21];
    const float* W1 = (const float*)d_in[22];
    const float* b1 = (const float*)d_in[23];
    const float* W2 = (const float*)d_in[24];
    const float* b2 = (const float*)d_in[25];
    const float* fc1w = (const float*)d_in[26];
    const float* fc1b = (const float*)d_in[27];
    const float* fc2w = (const float*)d_in[28];
    const float* fc2b = (const float*)d_in[29];
    const float* fc3w = (const float*)d_in[30];
    const float* fc3b = (const float*)d_in[31];
    const float* fc4w = (const float*)d_in[32];
    const float* fc4b = (const float*)d_in[33];

    float* ws  = (float*)d_ws;
    float* XGF  = ws;                          // [2048*512]
    float* XGR  = XGF + T_SEQ * G4;            // [2048*512]
    float* HF0  = XGR + T_SEQ * G4;            // [2048*128]
    float* HR0  = HF0 + T_SEQ * HID;           // [2048*128]
    float* GVEC = HR0 + T_SEQ * HID;           // [256]
    float* SUM  = GVEC + 256;                  // [128]
    float* AGG  = SUM + 128;                   // [50000*128]

    hipMemsetAsync(AGG, 0, (size_t)N_NODES * HID * sizeof(float), stream);
    hipMemsetAsync(SUM, 0, 128 * sizeof(float), stream);

    // ---- graph branch ----
    scatter_kernel<<<(N_EDGES * 32) / 256, 256, 0, stream>>>(esrc, edst, ew, feat, AGG);
    gconv1_kernel<<<N_NODES / NPB, 128, 0, stream>>>(W1, b1, AGG);
    hop2_reduce<<<2048, 256, 0, stream>>>(esrc, ew, AGG, SUM);

    // ---- LSTM branch ----
    xg0_kernel<<<(2 * T_SEQ * G4) / 256, 256, 0, stream>>>(
        g_mol, w_ih_l0, b_ih_l0, b_hh_l0, w_ih_l0r, b_ih_l0r, b_hh_l0r, XGF, XGR);
    lstm_scan<<<2, 512, 0, stream>>>(XGF, XGR, w_hh_l0, w_hh_l0r, HF0, HR0, nullptr, 1);
    xg1_kernel<<<(2 * 512 * G4) / 256, 256, 0, stream>>>(
        HF0, HR0, w_ih_l1, b_ih_l1, b_hh_l1, w_ih_l1r, b_ih_l1r, b_hh_l1r, XGF, XGR);
    lstm_scan<<<2, 512, 0, stream>>>(XGF, XGR, w_hh_l1, w_hh_l1r, nullptr, nullptr, GVEC, 0);

    // ---- head ----
    head_kernel<<<1, 640, 0, stream>>>(SUM, W2, b2, GVEC, kmer,
                                       fc1w, fc1b, fc2w, fc2b, fc3w, fc3b, fc4w, fc4b,
                                       (float*)d_out);
}

// Round 4
// 5831.809 us; speedup vs baseline: 5.6645x; 1.3482x over previous
//
#include <hip/hip_runtime.h>
#include <hip/hip_bf16.h>

#define T_SEQ 2048
#define HID 128
#define G4 512           // 4*HID gates
#define N_NODES 50000
#define N_EDGES 800000

__device__ __forceinline__ float fast_sigmoid(float x) {
    return 1.0f / (1.0f + __expf(-x));
}
__device__ __forceinline__ float fast_tanh(float x) {
    // NaN-safe: x->+inf => 1-0, x->-inf => 1-2
    return 1.0f - 2.0f / (__expf(2.0f * x) + 1.0f);
}

// ---------------- xg precompute, layer 0 (Din=17) ----------------
__global__ void xg0_kernel(const float* __restrict__ g_mol,
                           const float* __restrict__ wf, const float* __restrict__ bfi, const float* __restrict__ bfh,
                           const float* __restrict__ wr, const float* __restrict__ bri, const float* __restrict__ brh,
                           float* __restrict__ xg_f, float* __restrict__ xg_r)
{
    int gid = blockIdx.x * blockDim.x + threadIdx.x;
    int j = gid & (G4 - 1);
    int rest = gid >> 9;
    int t = rest & (T_SEQ - 1);
    int dir = rest >> 11;
    const float* w  = dir ? wr  : wf;
    const float* bi = dir ? bri : bfi;
    const float* bh = dir ? brh : bfh;
    float* xg = dir ? xg_r : xg_f;
    const float* x  = g_mol + t * 17;
    const float* wj = w + j * 17;
    float acc = bi[j] + bh[j];
    #pragma unroll
    for (int k = 0; k < 17; ++k) acc += x[k] * wj[k];
    xg[t * G4 + j] = acc;
}

// ---------------- xg precompute, layer 1 (Din=256 = concat[hf0,hr0]) ----------------
__global__ void xg1_kernel(const float* __restrict__ hf0, const float* __restrict__ hr0,
                           const float* __restrict__ wf, const float* __restrict__ bfi, const float* __restrict__ bfh,
                           const float* __restrict__ wr, const float* __restrict__ bri, const float* __restrict__ brh,
                           float* __restrict__ xg_f, float* __restrict__ xg_r)
{
    int gid = blockIdx.x * blockDim.x + threadIdx.x;
    int j = gid & (G4 - 1);
    int rest = gid >> 9;
    int tb = rest & 511;
    int dir = rest >> 9;
    const float* w  = dir ? wr  : wf;
    const float* bi = dir ? bri : bfi;
    const float* bh = dir ? brh : bfh;
    float* xg = dir ? xg_r : xg_f;
    int t0 = tb * 4;

    float b = bi[j] + bh[j];
    float a0 = b, a1 = b, a2 = b, a3 = b;
    const float4* wrow = reinterpret_cast<const float4*>(w + j * 256);
    const float4* hf = reinterpret_cast<const float4*>(hf0 + t0 * HID);
    const float4* hr = reinterpret_cast<const float4*>(hr0 + t0 * HID);
    #pragma unroll 8
    for (int k = 0; k < 32; ++k) {
        float4 wv = wrow[k];
        float4 v0 = hf[k], v1 = hf[32 + k], v2 = hf[64 + k], v3 = hf[96 + k];
        a0 += wv.x*v0.x + wv.y*v0.y + wv.z*v0.z + wv.w*v0.w;
        a1 += wv.x*v1.x + wv.y*v1.y + wv.z*v1.z + wv.w*v1.w;
        a2 += wv.x*v2.x + wv.y*v2.y + wv.z*v2.z + wv.w*v2.w;
        a3 += wv.x*v3.x + wv.y*v3.y + wv.z*v3.z + wv.w*v3.w;
    }
    #pragma unroll 8
    for (int k = 0; k < 32; ++k) {
        float4 wv = wrow[32 + k];
        float4 v0 = hr[k], v1 = hr[32 + k], v2 = hr[64 + k], v3 = hr[96 + k];
        a0 += wv.x*v0.x + wv.y*v0.y + wv.z*v0.z + wv.w*v0.w;
        a1 += wv.x*v1.x + wv.y*v1.y + wv.z*v1.z + wv.w*v1.w;
        a2 += wv.x*v2.x + wv.y*v2.y + wv.z*v2.z + wv.w*v2.w;
        a3 += wv.x*v3.x + wv.y*v3.y + wv.z*v3.z + wv.w*v3.w;
    }
    xg[(t0 + 0) * G4 + j] = a0;
    xg[(t0 + 1) * G4 + j] = a1;
    xg[(t0 + 2) * G4 + j] = a2;
    xg[(t0 + 3) * G4 + j] = a3;
}

// ---------------- the sequential LSTM scan: one block per direction ----------------
// 1024 threads; gate row j is SPLIT across two threads (j, half): each holds
// 64 weights = 16 float4 = 64 VGPRs. R3 post-mortem: a 128-float per-thread
// array (VGPR=100 < 128 needed) made the allocator rematerialize the weight
// loads every timestep -> 4.4 GB FETCH/dispatch, L2-BW-bound. 64 floats sits
// safely inside the 128-VGPR occupancy tier so weights stay register-resident.
__global__ __launch_bounds__(1024, 4)
void lstm_scan(const float* __restrict__ xg_f, const float* __restrict__ xg_r,
               const float* __restrict__ whh_f, const float* __restrict__ whh_r,
               float* __restrict__ out_f, float* __restrict__ out_r,
               float* __restrict__ gvec, int write_out)
{
    const int dir = blockIdx.x;            // 0 fwd, 1 rev
    const int tid = threadIdx.x;           // 0..1023
    const int j = tid & (G4 - 1);          // gate row 0..511
    const int half = tid >> 9;             // 0: k=0..63, 1: k=64..127
    const float* xg  = dir ? xg_r  : xg_f;
    const float* whh = dir ? whh_r : whh_f;
    float* out = dir ? out_r : out_f;

    __shared__ float h_s[HID];
    __shared__ float g_s[G4];      // half0 partial + xv
    __shared__ float part_s[G4];   // half1 partial

    float4 w4[16];
    const float4* wrow = reinterpret_cast<const float4*>(whh + j * HID + half * 64);
    #pragma unroll
    for (int k = 0; k < 16; ++k) w4[k] = wrow[k];

    if (tid < HID) h_s[tid] = 0.0f;
    float c = 0.0f;
    float msum = 0.0f;
    __syncthreads();

    int t0 = dir ? (T_SEQ - 1) : 0;
    float xv = (half == 0) ? xg[t0 * G4 + j] : 0.0f;   // prefetched current-step input gate

    for (int s = 0; s < T_SEQ; ++s) {
        int s2 = (s + 1 < T_SEQ) ? (s + 1) : s;
        int t      = dir ? (T_SEQ - 1 - s)  : s;
        int t_next = dir ? (T_SEQ - 1 - s2) : s2;
        float xv_n = (half == 0) ? xg[t_next * G4 + j] : 0.0f;  // prefetch next step

        const float4* h4 = reinterpret_cast<const float4*>(h_s + half * 64);
        float a0 = 0.f, a1 = 0.f, a2 = 0.f, a3 = 0.f;
        #pragma unroll
        for (int k = 0; k < 16; ++k) {     // FULL unroll: static w4[k] indices
            float4 hv = h4[k];
            a0 += w4[k].x * hv.x;
            a1 += w4[k].y * hv.y;
            a2 += w4[k].z * hv.z;
            a3 += w4[k].w * hv.w;
        }
        float p = (a0 + a1) + (a2 + a3);
        if (half) part_s[j] = p;           // wave-uniform branch (tid>=512 waves)
        else      g_s[j] = p + xv;
        __syncthreads();
        if (tid < HID) {
            float ig = fast_sigmoid(g_s[tid]           + part_s[tid]);
            float fg = fast_sigmoid(g_s[HID + tid]     + part_s[HID + tid]);
            float gg = fast_tanh(   g_s[2 * HID + tid] + part_s[2 * HID + tid]);
            float og = fast_sigmoid(g_s[3 * HID + tid] + part_s[3 * HID + tid]);
            c = fg * c + ig * gg;
            float hh = og * fast_tanh(c);
            h_s[tid] = hh;
            if (write_out) out[t * HID + tid] = hh;
            msum += hh;
        }
        __syncthreads();
        xv = xv_n;
    }
    if (gvec != nullptr && tid < HID) gvec[dir * HID + tid] = msum * (1.0f / (float)T_SEQ);
}

// ---------------- GraphConv hop 1: weighted scatter-add ----------------
__global__ void scatter_kernel(const int* __restrict__ esrc, const int* __restrict__ edst,
                               const float* __restrict__ ew, const float* __restrict__ feat,
                               float* __restrict__ agg)
{
    int gid = blockIdx.x * blockDim.x + threadIdx.x;
    int e = gid >> 5;
    int c = gid & 31;
    int s = esrc[e], d = edst[e];
    float w = ew[e];
    float4 v = reinterpret_cast<const float4*>(feat)[(long)s * 32 + c];
    float* ap = agg + (long)d * HID + (c << 2);
    atomicAdd(ap + 0, w * v.x);
    atomicAdd(ap + 1, w * v.y);
    atomicAdd(ap + 2, w * v.z);
    atomicAdd(ap + 3, w * v.w);
}

// ---------------- hop 1 linear + relu, in-place on agg, W1 staged in LDS ----------------
#define NPB 50
__global__ __launch_bounds__(128)
void gconv1_kernel(const float* __restrict__ W1, const float* __restrict__ b1,
                   float* __restrict__ agg)
{
    __shared__ float w_s[128 * 128];   // 64 KB
    __shared__ float row_s[2][HID];
    int j = threadIdx.x;
    for (int i = j; i < 128 * 128; i += 128) w_s[i] = W1[i];
    float bj = b1[j];
    __syncthreads();
    int base = blockIdx.x * NPB;
    for (int n = base; n < base + NPB; n += 2) {
        row_s[0][j] = agg[(long)n * HID + j];
        row_s[1][j] = agg[(long)(n + 1) * HID + j];
        __syncthreads();
        float a0 = bj, a1 = bj;
        #pragma unroll 8
        for (int k = 0; k < 128; ++k) {
            float w = w_s[k * 128 + j];
            a0 += row_s[0][k] * w;
            a1 += row_s[1][k] * w;
        }
        __syncthreads();
        agg[(long)n * HID + j]       = fmaxf(a0, 0.0f);
        agg[(long)(n + 1) * HID + j] = fmaxf(a1, 0.0f);
    }
}

// ---------------- hop 2 collapsed: s[k] = sum_e w_e * h[src_e][k] ----------------
__global__ void hop2_reduce(const int* __restrict__ esrc, const float* __restrict__ ew,
                            const float* __restrict__ h, float* __restrict__ s_out)
{
    int tid = threadIdx.x;        // 256 = 8 edge-lanes x 32 chunks
    int c = tid & 31;
    int g = tid >> 5;
    float ax = 0.f, ay = 0.f, az = 0.f, aw = 0.f;
    const float4* h4 = reinterpret_cast<const float4*>(h);
    for (long e = (long)blockIdx.x * 8 + g; e < N_EDGES; e += (long)gridDim.x * 8) {
        float wgt = ew[e];
        int sidx = esrc[e];
        float4 v = h4[(long)sidx * 32 + c];
        ax += wgt * v.x; ay += wgt * v.y; az += wgt * v.z; aw += wgt * v.w;
    }
    __shared__ float red[256 * 4];
    red[tid * 4 + 0] = ax; red[tid * 4 + 1] = ay;
    red[tid * 4 + 2] = az; red[tid * 4 + 3] = aw;
    __syncthreads();
    if (tid < 32) {
        float r0 = 0.f, r1 = 0.f, r2 = 0.f, r3 = 0.f;
        for (int gg = 0; gg < 8; ++gg) {
            int b = (gg * 32 + tid) * 4;
            r0 += red[b + 0]; r1 += red[b + 1]; r2 += red[b + 2]; r3 += red[b + 3];
        }
        atomicAdd(&s_out[tid * 4 + 0], r0);
        atomicAdd(&s_out[tid * 4 + 1], r1);
        atomicAdd(&s_out[tid * 4 + 2], r2);
        atomicAdd(&s_out[tid * 4 + 3], r3);
    }
}

// ---------------- head: hg = (s/N)@W2 + b2; concat; 4-layer MLP ----------------
__global__ __launch_bounds__(640)
void head_kernel(const float* __restrict__ s_in, const float* __restrict__ W2, const float* __restrict__ b2,
                 const float* __restrict__ gvec, const float* __restrict__ kmer,
                 const float* __restrict__ fc1w, const float* __restrict__ fc1b,
                 const float* __restrict__ fc2w, const float* __restrict__ fc2b,
                 const float* __restrict__ fc3w, const float* __restrict__ fc3b,
                 const float* __restrict__ fc4w, const float* __restrict__ fc4b,
                 float* __restrict__ out)
{
    __shared__ float feat[1152];
    __shared__ float a1[576];
    __shared__ float a2[256];
    __shared__ float a3[64];
    int tid = threadIdx.x;
    if (tid < 256) {
        float acc = b2[tid];
        const float inv_n = 1.0f / (float)N_NODES;
        for (int k = 0; k < HID; ++k)
            acc += (s_in[k] * inv_n) * W2[k * 256 + tid];
        feat[tid] = acc;
    } else if (tid < 512) {
        feat[tid] = gvec[tid - 256];
    }
    if (tid < 638) feat[512 + tid] = kmer[tid];
    __syncthreads();

    if (tid < 575) {
        const float2* wr = reinterpret_cast<const float2*>(fc1w + (long)tid * 1150);
        const float2* f2 = reinterpret_cast<const float2*>(feat);
        float acc = fc1b[tid];
        for (int k = 0; k < 575; ++k) {
            float2 wv = wr[k]; float2 fv = f2[k];
            acc += wv.x * fv.x + wv.y * fv.y;
        }
        a1[tid] = fmaxf(acc, 0.0f);
    }
    __syncthreads();
    if (tid < 256) {
        const float* wr = fc2w + (long)tid * 575;
        float acc = fc2b[tid];
        for (int k = 0; k < 575; ++k) acc += a1[k] * wr[k];
        a2[tid] = fmaxf(acc, 0.0f);
    }
    __syncthreads();
    if (tid < 64) {
        const float4* wr = reinterpret_cast<const float4*>(fc3w + (long)tid * 256);
        const float4* av4 = reinterpret_cast<const float4*>(a2);
        float acc = fc3b[tid];
        for (int k = 0; k < 64; ++k) {
            float4 wv = wr[k]; float4 av = av4[k];
            acc += wv.x*av.x + wv.y*av.y + wv.z*av.z + wv.w*av.w;
        }
        a3[tid] = fmaxf(acc, 0.0f);
    }
    __syncthreads();
    if (tid == 0) {
        float acc = fc4b[0];
        for (int k = 0; k < 64; ++k) acc += a3[k] * fc4w[k];
        out[0] = acc;
    }
}

extern "C" void kernel_launch(void* const* d_in, const int* in_sizes, int n_in,
                              void* d_out, int out_size, void* d_ws, size_t ws_size,
                              hipStream_t stream)
{
    const float* g_mol = (const float*)d_in[0];
    const float* feat  = (const float*)d_in[1];
    const int*   esrc  = (const int*)d_in[2];
    const int*   edst  = (const int*)d_in[3];
    const float* ew    = (const float*)d_in[4];
    const float* kmer  = (const float*)d_in[5];
    const float* w_ih_l0  = (const float*)d_in[6];
    const float* w_hh_l0  = (const float*)d_in[7];
    const float* b_ih_l0  = (const float*)d_in[8];
    const float* b_hh_l0  = (const float*)d_in[9];
    const float* w_ih_l0r = (const float*)d_in[10];
    const float* w_hh_l0r = (const float*)d_in[11];
    const float* b_ih_l0r = (const float*)d_in[12];
    const float* b_hh_l0r = (const float*)d_in[13];
    const float* w_ih_l1  = (const float*)d_in[14];
    const float* w_hh_l1  = (const float*)d_in[15];
    const float* b_ih_l1  = (const float*)d_in[16];
    const float* b_hh_l1  = (const float*)d_in[17];
    const float* w_ih_l1r = (const float*)d_in[18];
    const float* w_hh_l1r = (const float*)d_in[19];
    const float* b_ih_l1r = (const float*)d_in[20];
    const float* b_hh_l1r = (const float*)d_in[21];
    const float* W1 = (const float*)d_in[22];
    const float* b1 = (const float*)d_in[23];
    const float* W2 = (const float*)d_in[24];
    const float* b2 = (const float*)d_in[25];
    const float* fc1w = (const float*)d_in[26];
    const float* fc1b = (const float*)d_in[27];
    const float* fc2w = (const float*)d_in[28];
    const float* fc2b = (const float*)d_in[29];
    const float* fc3w = (const float*)d_in[30];
    const float* fc3b = (const float*)d_in[31];
    const float* fc4w = (const float*)d_in[32];
    const float* fc4b = (const float*)d_in[33];

    float* ws  = (float*)d_ws;
    float* XGF  = ws;                          // [2048*512]
    float* XGR  = XGF + T_SEQ * G4;            // [2048*512]
    float* HF0  = XGR + T_SEQ * G4;            // [2048*128]
    float* HR0  = HF0 + T_SEQ * HID;           // [2048*128]
    float* GVEC = HR0 + T_SEQ * HID;           // [256]
    float* SUM  = GVEC + 256;                  // [128]
    float* AGG  = SUM + 128;                   // [50000*128]

    hipMemsetAsync(AGG, 0, (size_t)N_NODES * HID * sizeof(float), stream);
    hipMemsetAsync(SUM, 0, 128 * sizeof(float), stream);

    // ---- graph branch ----
    scatter_kernel<<<(N_EDGES * 32) / 256, 256, 0, stream>>>(esrc, edst, ew, feat, AGG);
    gconv1_kernel<<<N_NODES / NPB, 128, 0, stream>>>(W1, b1, AGG);
    hop2_reduce<<<2048, 256, 0, stream>>>(esrc, ew, AGG, SUM);

    // ---- LSTM branch ----
    xg0_kernel<<<(2 * T_SEQ * G4) / 256, 256, 0, stream>>>(
        g_mol, w_ih_l0, b_ih_l0, b_hh_l0, w_ih_l0r, b_ih_l0r, b_hh_l0r, XGF, XGR);
    lstm_scan<<<2, 1024, 0, stream>>>(XGF, XGR, w_hh_l0, w_hh_l0r, HF0, HR0, nullptr, 1);
    xg1_kernel<<<(2 * 512 * G4) / 256, 256, 0, stream>>>(
        HF0, HR0, w_ih_l1, b_ih_l1, b_hh_l1, w_ih_l1r, b_ih_l1r, b_hh_l1r, XGF, XGR);
    lstm_scan<<<2, 1024, 0, stream>>>(XGF, XGR, w_hh_l1, w_hh_l1r, nullptr, nullptr, GVEC, 0);

    // ---- head ----
    head_kernel<<<1, 640, 0, stream>>>(SUM, W2, b2, GVEC, kmer,
                                       fc1w, fc1b, fc2w, fc2b, fc3w, fc3b, fc4w, fc4b,
                                       (float*)d_out);
}

// Round 5
// 5598.171 us; speedup vs baseline: 5.9009x; 1.0417x over previous
//
#include <hip/hip_runtime.h>
#include <hip/hip_bf16.h>

#define T_SEQ 2048
#define HID 128
#define G4 512           // 4*HID gates
#define N_NODES 50000
#define N_EDGES 800000

__device__ __forceinline__ float fast_sigmoid(float x) {
    return 1.0f / (1.0f + __expf(-x));
}
__device__ __forceinline__ float fast_tanh(float x) {
    // NaN-safe: x->+inf => 1-0, x->-inf => 1-2
    return 1.0f - 2.0f / (__expf(2.0f * x) + 1.0f);
}

// ---------------- xg precompute, layer 0 (Din=17) ----------------
__global__ void xg0_kernel(const float* __restrict__ g_mol,
                           const float* __restrict__ wf, const float* __restrict__ bfi, const float* __restrict__ bfh,
                           const float* __restrict__ wr, const float* __restrict__ bri, const float* __restrict__ brh,
                           float* __restrict__ xg_f, float* __restrict__ xg_r)
{
    int gid = blockIdx.x * blockDim.x + threadIdx.x;
    int j = gid & (G4 - 1);
    int rest = gid >> 9;
    int t = rest & (T_SEQ - 1);
    int dir = rest >> 11;
    const float* w  = dir ? wr  : wf;
    const float* bi = dir ? bri : bfi;
    const float* bh = dir ? brh : bfh;
    float* xg = dir ? xg_r : xg_f;
    const float* x  = g_mol + t * 17;
    const float* wj = w + j * 17;
    float acc = bi[j] + bh[j];
    #pragma unroll
    for (int k = 0; k < 17; ++k) acc += x[k] * wj[k];
    xg[t * G4 + j] = acc;
}

// ---------------- xg precompute, layer 1 (Din=256 = concat[hf0,hr0]) ----------------
__global__ void xg1_kernel(const float* __restrict__ hf0, const float* __restrict__ hr0,
                           const float* __restrict__ wf, const float* __restrict__ bfi, const float* __restrict__ bfh,
                           const float* __restrict__ wr, const float* __restrict__ bri, const float* __restrict__ brh,
                           float* __restrict__ xg_f, float* __restrict__ xg_r)
{
    int gid = blockIdx.x * blockDim.x + threadIdx.x;
    int j = gid & (G4 - 1);
    int rest = gid >> 9;
    int tb = rest & 511;
    int dir = rest >> 9;
    const float* w  = dir ? wr  : wf;
    const float* bi = dir ? bri : bfi;
    const float* bh = dir ? brh : bfh;
    float* xg = dir ? xg_r : xg_f;
    int t0 = tb * 4;

    float b = bi[j] + bh[j];
    float a0 = b, a1 = b, a2 = b, a3 = b;
    const float4* wrow = reinterpret_cast<const float4*>(w + j * 256);
    const float4* hf = reinterpret_cast<const float4*>(hf0 + t0 * HID);
    const float4* hr = reinterpret_cast<const float4*>(hr0 + t0 * HID);
    #pragma unroll 8
    for (int k = 0; k < 32; ++k) {
        float4 wv = wrow[k];
        float4 v0 = hf[k], v1 = hf[32 + k], v2 = hf[64 + k], v3 = hf[96 + k];
        a0 += wv.x*v0.x + wv.y*v0.y + wv.z*v0.z + wv.w*v0.w;
        a1 += wv.x*v1.x + wv.y*v1.y + wv.z*v1.z + wv.w*v1.w;
        a2 += wv.x*v2.x + wv.y*v2.y + wv.z*v2.z + wv.w*v2.w;
        a3 += wv.x*v3.x + wv.y*v3.y + wv.z*v3.z + wv.w*v3.w;
    }
    #pragma unroll 8
    for (int k = 0; k < 32; ++k) {
        float4 wv = wrow[32 + k];
        float4 v0 = hr[k], v1 = hr[32 + k], v2 = hr[64 + k], v3 = hr[96 + k];
        a0 += wv.x*v0.x + wv.y*v0.y + wv.z*v0.z + wv.w*v0.w;
        a1 += wv.x*v1.x + wv.y*v1.y + wv.z*v1.z + wv.w*v1.w;
        a2 += wv.x*v2.x + wv.y*v2.y + wv.z*v2.z + wv.w*v2.w;
        a3 += wv.x*v3.x + wv.y*v3.y + wv.z*v3.z + wv.w*v3.w;
    }
    xg[(t0 + 0) * G4 + j] = a0;
    xg[(t0 + 1) * G4 + j] = a1;
    xg[(t0 + 2) * G4 + j] = a2;
    xg[(t0 + 3) * G4 + j] = a3;
}

// ---------------- the sequential LSTM scan: one block per direction ----------------
// 1024 threads; gate row j SPLIT across two threads (j, half): 64 weights each.
// R3/R4 post-mortem: compiler SINKS the loop-invariant weight loads into the
// 2048-step loop (VGPR=48 < 64 needed, FETCH 4.4 GB/dispatch) regardless of
// VGPR budget. Fix: opaque asm "+v" on each loaded component — blocks the
// rematerialization/sinking, forcing true register residency.
__global__ __launch_bounds__(1024, 2)
void lstm_scan(const float* __restrict__ xg_f, const float* __restrict__ xg_r,
               const float* __restrict__ whh_f, const float* __restrict__ whh_r,
               float* __restrict__ out_f, float* __restrict__ out_r,
               float* __restrict__ gvec, int write_out)
{
    const int dir = blockIdx.x;            // 0 fwd, 1 rev
    const int tid = threadIdx.x;           // 0..1023
    const int j = tid & (G4 - 1);          // gate row 0..511
    const int half = tid >> 9;             // 0: k=0..63, 1: k=64..127
    const float* xg  = dir ? xg_r  : xg_f;
    const float* whh = dir ? whh_r : whh_f;
    float* out = dir ? out_r : out_f;

    __shared__ float h_s[HID];
    __shared__ float g_s[G4];      // half0 partial + xv
    __shared__ float part_s[G4];   // half1 partial

    float4 w4[16];
    const float4* wrow = reinterpret_cast<const float4*>(whh + j * HID + half * 64);
    #pragma unroll
    for (int k = 0; k < 16; ++k) {
        w4[k] = wrow[k];
        // Pin in VGPRs: value becomes opaque -> compiler cannot re-load/sink.
        asm volatile("" : "+v"(w4[k].x), "+v"(w4[k].y), "+v"(w4[k].z), "+v"(w4[k].w));
    }

    if (tid < HID) h_s[tid] = 0.0f;
    float c = 0.0f;
    float msum = 0.0f;
    __syncthreads();

    int t0 = dir ? (T_SEQ - 1) : 0;
    float xv = (half == 0) ? xg[t0 * G4 + j] : 0.0f;   // prefetched current-step input gate

    for (int s = 0; s < T_SEQ; ++s) {
        int s2 = (s + 1 < T_SEQ) ? (s + 1) : s;
        int t      = dir ? (T_SEQ - 1 - s)  : s;
        int t_next = dir ? (T_SEQ - 1 - s2) : s2;
        float xv_n = (half == 0) ? xg[t_next * G4 + j] : 0.0f;  // prefetch next step

        const float4* h4 = reinterpret_cast<const float4*>(h_s + half * 64);
        float a0 = 0.f, a1 = 0.f, a2 = 0.f, a3 = 0.f;
        #pragma unroll
        for (int k = 0; k < 16; ++k) {     // FULL unroll: static w4[k] indices
            float4 hv = h4[k];
            a0 += w4[k].x * hv.x;
            a1 += w4[k].y * hv.y;
            a2 += w4[k].z * hv.z;
            a3 += w4[k].w * hv.w;
        }
        float p = (a0 + a1) + (a2 + a3);
        if (half) part_s[j] = p;           // wave-uniform branch (tid>=512 waves)
        else      g_s[j] = p + xv;
        __syncthreads();
        if (tid < HID) {
            float ig = fast_sigmoid(g_s[tid]           + part_s[tid]);
            float fg = fast_sigmoid(g_s[HID + tid]     + part_s[HID + tid]);
            float gg = fast_tanh(   g_s[2 * HID + tid] + part_s[2 * HID + tid]);
            float og = fast_sigmoid(g_s[3 * HID + tid] + part_s[3 * HID + tid]);
            c = fg * c + ig * gg;
            float hh = og * fast_tanh(c);
            h_s[tid] = hh;
            if (write_out) out[t * HID + tid] = hh;
            msum += hh;
        }
        __syncthreads();
        xv = xv_n;
    }
    if (gvec != nullptr && tid < HID) gvec[dir * HID + tid] = msum * (1.0f / (float)T_SEQ);
}

// ---------------- GraphConv hop 1: weighted scatter-add ----------------
__global__ void scatter_kernel(const int* __restrict__ esrc, const int* __restrict__ edst,
                               const float* __restrict__ ew, const float* __restrict__ feat,
                               float* __restrict__ agg)
{
    int gid = blockIdx.x * blockDim.x + threadIdx.x;
    int e = gid >> 5;
    int c = gid & 31;
    int s = esrc[e], d = edst[e];
    float w = ew[e];
    float4 v = reinterpret_cast<const float4*>(feat)[(long)s * 32 + c];
    float* ap = agg + (long)d * HID + (c << 2);
    atomicAdd(ap + 0, w * v.x);
    atomicAdd(ap + 1, w * v.y);
    atomicAdd(ap + 2, w * v.z);
    atomicAdd(ap + 3, w * v.w);
}

// ---------------- hop 1 linear + relu, in-place on agg, W1 staged in LDS ----------------
#define NPB 50
__global__ __launch_bounds__(128)
void gconv1_kernel(const float* __restrict__ W1, const float* __restrict__ b1,
                   float* __restrict__ agg)
{
    __shared__ float w_s[128 * 128];   // 64 KB
    __shared__ float row_s[2][HID];
    int j = threadIdx.x;
    for (int i = j; i < 128 * 128; i += 128) w_s[i] = W1[i];
    float bj = b1[j];
    __syncthreads();
    int base = blockIdx.x * NPB;
    for (int n = base; n < base + NPB; n += 2) {
        row_s[0][j] = agg[(long)n * HID + j];
        row_s[1][j] = agg[(long)(n + 1) * HID + j];
        __syncthreads();
        float a0 = bj, a1 = bj;
        #pragma unroll 8
        for (int k = 0; k < 128; ++k) {
            float w = w_s[k * 128 + j];
            a0 += row_s[0][k] * w;
            a1 += row_s[1][k] * w;
        }
        __syncthreads();
        agg[(long)n * HID + j]       = fmaxf(a0, 0.0f);
        agg[(long)(n + 1) * HID + j] = fmaxf(a1, 0.0f);
    }
}

// ---------------- hop 2 collapsed: s[k] = sum_e w_e * h[src_e][k] ----------------
__global__ void hop2_reduce(const int* __restrict__ esrc, const float* __restrict__ ew,
                            const float* __restrict__ h, float* __restrict__ s_out)
{
    int tid = threadIdx.x;        // 256 = 8 edge-lanes x 32 chunks
    int c = tid & 31;
    int g = tid >> 5;
    float ax = 0.f, ay = 0.f, az = 0.f, aw = 0.f;
    const float4* h4 = reinterpret_cast<const float4*>(h);
    for (long e = (long)blockIdx.x * 8 + g; e < N_EDGES; e += (long)gridDim.x * 8) {
        float wgt = ew[e];
        int sidx = esrc[e];
        float4 v = h4[(long)sidx * 32 + c];
        ax += wgt * v.x; ay += wgt * v.y; az += wgt * v.z; aw += wgt * v.w;
    }
    __shared__ float red[256 * 4];
    red[tid * 4 + 0] = ax; red[tid * 4 + 1] = ay;
    red[tid * 4 + 2] = az; red[tid * 4 + 3] = aw;
    __syncthreads();
    if (tid < 32) {
        float r0 = 0.f, r1 = 0.f, r2 = 0.f, r3 = 0.f;
        for (int gg = 0; gg < 8; ++gg) {
            int b = (gg * 32 + tid) * 4;
            r0 += red[b + 0]; r1 += red[b + 1]; r2 += red[b + 2]; r3 += red[b + 3];
        }
        atomicAdd(&s_out[tid * 4 + 0], r0);
        atomicAdd(&s_out[tid * 4 + 1], r1);
        atomicAdd(&s_out[tid * 4 + 2], r2);
        atomicAdd(&s_out[tid * 4 + 3], r3);
    }
}

// ---------------- head: hg = (s/N)@W2 + b2; concat; 4-layer MLP ----------------
__global__ __launch_bounds__(640)
void head_kernel(const float* __restrict__ s_in, const float* __restrict__ W2, const float* __restrict__ b2,
                 const float* __restrict__ gvec, const float* __restrict__ kmer,
                 const float* __restrict__ fc1w, const float* __restrict__ fc1b,
                 const float* __restrict__ fc2w, const float* __restrict__ fc2b,
                 const float* __restrict__ fc3w, const float* __restrict__ fc3b,
                 const float* __restrict__ fc4w, const float* __restrict__ fc4b,
                 float* __restrict__ out)
{
    __shared__ float feat[1152];
    __shared__ float a1[576];
    __shared__ float a2[256];
    __shared__ float a3[64];
    int tid = threadIdx.x;
    if (tid < 256) {
        float acc = b2[tid];
        const float inv_n = 1.0f / (float)N_NODES;
        for (int k = 0; k < HID; ++k)
            acc += (s_in[k] * inv_n) * W2[k * 256 + tid];
        feat[tid] = acc;
    } else if (tid < 512) {
        feat[tid] = gvec[tid - 256];
    }
    if (tid < 638) feat[512 + tid] = kmer[tid];
    __syncthreads();

    if (tid < 575) {
        const float2* wr = reinterpret_cast<const float2*>(fc1w + (long)tid * 1150);
        const float2* f2 = reinterpret_cast<const float2*>(feat);
        float acc = fc1b[tid];
        for (int k = 0; k < 575; ++k) {
            float2 wv = wr[k]; float2 fv = f2[k];
            acc += wv.x * fv.x + wv.y * fv.y;
        }
        a1[tid] = fmaxf(acc, 0.0f);
    }
    __syncthreads();
    if (tid < 256) {
        const float* wr = fc2w + (long)tid * 575;
        float acc = fc2b[tid];
        for (int k = 0; k < 575; ++k) acc += a1[k] * wr[k];
        a2[tid] = fmaxf(acc, 0.0f);
    }
    __syncthreads();
    if (tid < 64) {
        const float4* wr = reinterpret_cast<const float4*>(fc3w + (long)tid * 256);
        const float4* av4 = reinterpret_cast<const float4*>(a2);
        float acc = fc3b[tid];
        for (int k = 0; k < 64; ++k) {
            float4 wv = wr[k]; float4 av = av4[k];
            acc += wv.x*av.x + wv.y*av.y + wv.z*av.z + wv.w*av.w;
        }
        a3[tid] = fmaxf(acc, 0.0f);
    }
    __syncthreads();
    if (tid == 0) {
        float acc = fc4b[0];
        for (int k = 0; k < 64; ++k) acc += a3[k] * fc4w[k];
        out[0] = acc;
    }
}

extern "C" void kernel_launch(void* const* d_in, const int* in_sizes, int n_in,
                              void* d_out, int out_size, void* d_ws, size_t ws_size,
                              hipStream_t stream)
{
    const float* g_mol = (const float*)d_in[0];
    const float* feat  = (const float*)d_in[1];
    const int*   esrc  = (const int*)d_in[2];
    const int*   edst  = (const int*)d_in[3];
    const float* ew    = (const float*)d_in[4];
    const float* kmer  = (const float*)d_in[5];
    const float* w_ih_l0  = (const float*)d_in[6];
    const float* w_hh_l0  = (const float*)d_in[7];
    const float* b_ih_l0  = (const float*)d_in[8];
    const float* b_hh_l0  = (const float*)d_in[9];
    const float* w_ih_l0r = (const float*)d_in[10];
    const float* w_hh_l0r = (const float*)d_in[11];
    const float* b_ih_l0r = (const float*)d_in[12];
    const float* b_hh_l0r = (const float*)d_in[13];
    const float* w_ih_l1  = (const float*)d_in[14];
    const float* w_hh_l1  = (const float*)d_in[15];
    const float* b_ih_l1  = (const float*)d_in[16];
    const float* b_hh_l1  = (const float*)d_in[17];
    const float* w_ih_l1r = (const float*)d_in[18];
    const float* w_hh_l1r = (const float*)d_in[19];
    const float* b_ih_l1r = (const float*)d_in[20];
    const float* b_hh_l1r = (const float*)d_in[21];
    const float* W1 = (const float*)d_in[22];
    const float* b1 = (const float*)d_in[23];
    const float* W2 = (const float*)d_in[24];
    const float* b2 = (const float*)d_in[25];
    const float* fc1w = (const float*)d_in[26];
    const float* fc1b = (const float*)d_in[27];
    const float* fc2w = (const float*)d_in[28];
    const float* fc2b = (const float*)d_in[29];
    const float* fc3w = (const float*)d_in[30];
    const float* fc3b = (const float*)d_in[31];
    const float* fc4w = (const float*)d_in[32];
    const float* fc4b = (const float*)d_in[33];

    float* ws  = (float*)d_ws;
    float* XGF  = ws;                          // [2048*512]
    float* XGR  = XGF + T_SEQ * G4;            // [2048*512]
    float* HF0  = XGR + T_SEQ * G4;            // [2048*128]
    float* HR0  = HF0 + T_SEQ * HID;           // [2048*128]
    float* GVEC = HR0 + T_SEQ * HID;           // [256]
    float* SUM  = GVEC + 256;                  // [128]
    float* AGG  = SUM + 128;                   // [50000*128]

    hipMemsetAsync(AGG, 0, (size_t)N_NODES * HID * sizeof(float), stream);
    hipMemsetAsync(SUM, 0, 128 * sizeof(float), stream);

    // ---- graph branch ----
    scatter_kernel<<<(N_EDGES * 32) / 256, 256, 0, stream>>>(esrc, edst, ew, feat, AGG);
    gconv1_kernel<<<N_NODES / NPB, 128, 0, stream>>>(W1, b1, AGG);
    hop2_reduce<<<2048, 256, 0, stream>>>(esrc, ew, AGG, SUM);

    // ---- LSTM branch ----
    xg0_kernel<<<(2 * T_SEQ * G4) / 256, 256, 0, stream>>>(
        g_mol, w_ih_l0, b_ih_l0, b_hh_l0, w_ih_l0r, b_ih_l0r, b_hh_l0r, XGF, XGR);
    lstm_scan<<<2, 1024, 0, stream>>>(XGF, XGR, w_hh_l0, w_hh_l0r, HF0, HR0, nullptr, 1);
    xg1_kernel<<<(2 * 512 * G4) / 256, 256, 0, stream>>>(
        HF0, HR0, w_ih_l1, b_ih_l1, b_hh_l1, w_ih_l1r, b_ih_l1r, b_hh_l1r, XGF, XGR);
    lstm_scan<<<2, 1024, 0, stream>>>(XGF, XGR, w_hh_l1, w_hh_l1r, nullptr, nullptr, GVEC, 0);

    // ---- head ----
    head_kernel<<<1, 640, 0, stream>>>(SUM, W2, b2, GVEC, kmer,
                                       fc1w, fc1b, fc2w, fc2b, fc3w, fc3b, fc4w, fc4b,
                                       (float*)d_out);
}